// Round 6
// baseline (837.605 us; speedup 1.0000x reference)
//
#include <hip/hip_runtime.h>
#include <hip/hip_bf16.h>

// DynamicMaskHead: N=2, C=8, H=128, W=192, n_inst=128, factor=2
#define NUM_INST 128
#define H_ 128
#define W_ 192
#define HW_ (H_ * W_)      // 24576
#define OH_ 256
#define OW_ 384
#define NPAR 169           // 80 + 64 + 8 + 8 + 8 + 1

typedef float v2f __attribute__((ext_vector_type(2)));

static __device__ __forceinline__ float bf2f(unsigned short u) {
    union { unsigned int i; float f; } v;
    v.i = ((unsigned int)u) << 16;
    return v.f;
}
static __device__ __forceinline__ float hi2f(unsigned int u) {
    union { unsigned int i; float f; } v;
    v.i = u & 0xFFFF0000u;
    return v.f;
}
static __device__ __forceinline__ float lo2f(unsigned int u) {
    union { unsigned int i; float f; } v;
    v.i = u << 16;
    return v.f;
}
static __device__ __forceinline__ unsigned int f2bf(float f) {
    unsigned int u = __float_as_uint(f);
    return (u + 0x7fffu + ((u >> 16) & 1u)) >> 16;
}
static __device__ __forceinline__ v2f pkfma(v2f a, v2f b, v2f c) {
    return __builtin_elementwise_fma(a, b, c);   // v_pk_fma_f32
}
static __device__ __forceinline__ v2f pkrelu(v2f a) {
    const v2f z = {0.0f, 0.0f};
    return __builtin_elementwise_max(a, z);
}

// K1: dynamic 3-layer MLP -> fp32 logits in workspace. 2 px/thread.
// R6 change: weights are wave-uniform (inst = blockIdx.y), so they are read
// through the SCALAR path (s_load -> SGPR -> fma s-operand) instead of LDS.
// R5 post-mortem: 45 ds_read_b128/unit x 96 waves/CU x 12cyc = 21.6us on the
// per-CU LDS pipe was the bottleneck (VALU only ~3.5us). This kernel has ZERO
// LDS usage and no barrier. Weight loads are interleaved per output channel
// so live SGPR ranges stay short.
__global__ __launch_bounds__(256, 4) void mlp_kernel(
    const void* __restrict__ mf_v,    // mask_feats  (2,8,128,192)
    const void* __restrict__ par_v,   // params      (128,169)
    const void* __restrict__ loc_v,   // locations   (128,2)
    const void* __restrict__ soi_v,   // sizes       (6,)
    const int*  __restrict__ im_inds, // (128,) int32
    const int*  __restrict__ fpn,     // (128,) int32
    float*      __restrict__ logits)  // (128, HW_) fp32 ws
{
    const int tid  = threadIdx.x;
    const int inst = blockIdx.y;

    // dtype probe: sizes_of_interest[0]==64.0 -> 0x42800000 iff fp32 tensors.
    // (R4/R5 counters: WRITE_SIZE=48MiB, FETCH~1.3MiB => dataset is fp32;
    //  probe kept as cheap correctness insurance.)
    const bool f32in = (*(const unsigned int*)soi_v) == 0x42800000u;

    const float*          pwf = (const float*)par_v + (size_t)inst * NPAR;
    const unsigned short* pwu = (const unsigned short*)par_v + (size_t)inst * NPAR;
    auto wld = [&](int k) -> float {            // uniform -> scalar load
        return f32in ? pwf[k] : bf2f(pwu[k]);
    };

    float lx, ly, soi;
    const int lvl = fpn[inst];
    if (f32in) {
        lx  = ((const float*)loc_v)[inst * 2 + 0];
        ly  = ((const float*)loc_v)[inst * 2 + 1];
        soi = ((const float*)soi_v)[lvl];
    } else {
        lx  = bf2f(((const unsigned short*)loc_v)[inst * 2 + 0]);
        ly  = bf2f(((const unsigned short*)loc_v)[inst * 2 + 1]);
        soi = bf2f(((const unsigned short*)soi_v)[lvl]);
    }
    const float invs = 1.0f / soi;
    const size_t fo  = (size_t)im_inds[inst] * 8 * HW_;

    const int p0 = (blockIdx.x * 256 + tid) * 2;   // 2 px, same row (192 even)
    const int r  = p0 / W_;
    const int c0 = p0 - r * W_;

    const float dy  = (ly - (float)(r * 8 + 4)) * invs;
    const float dx0 = (lx - (float)(c0 * 8 + 4)) * invs;

    v2f x[9];                          // 0 = dx pair, 1..8 = feat channels
    x[0] = (v2f){dx0, dx0 - 8.0f * invs};
    if (f32in) {
        const float* fb = (const float*)mf_v + fo + (r * W_ + c0);
#pragma unroll
        for (int ch = 0; ch < 8; ch++) {
            float2 f = *(const float2*)(fb + ch * HW_);   // 8B aligned
            x[1 + ch] = (v2f){f.x, f.y};
        }
    } else {
        const unsigned short* fb = (const unsigned short*)mf_v + fo + (r * W_ + c0);
#pragma unroll
        for (int ch = 0; ch < 8; ch++) {
            unsigned int f = *(const unsigned int*)(fb + ch * HW_);
            x[1 + ch] = (v2f){lo2f(f), hi2f(f)};
        }
    }

    // layer 0: 10 -> 8, relu. weights [dx, dy, f0..f7]; dy folded into bias.
    v2f h1[8];
#pragma unroll
    for (int o = 0; o < 8; o++) {
        float wv[10];
#pragma unroll
        for (int i = 0; i < 10; i++) wv[i] = wld(o * 10 + i);
        const float b0 = wld(152 + o);
        const float t  = fmaf(wv[1], dy, b0);
        v2f a = (v2f){t, t};
        a = pkfma((v2f){wv[0], wv[0]}, x[0], a);
#pragma unroll
        for (int j = 0; j < 8; j++)
            a = pkfma((v2f){wv[2 + j], wv[2 + j]}, x[1 + j], a);
        h1[o] = pkrelu(a);
    }

    // layer 1: 8 -> 8, relu
    v2f h2[8];
#pragma unroll
    for (int o = 0; o < 8; o++) {
        float wv[8];
#pragma unroll
        for (int i = 0; i < 8; i++) wv[i] = wld(80 + o * 8 + i);
        const float b1 = wld(160 + o);
        v2f a = (v2f){b1, b1};
#pragma unroll
        for (int i = 0; i < 8; i++)
            a = pkfma((v2f){wv[i], wv[i]}, h1[i], a);
        h2[o] = pkrelu(a);
    }

    // layer 2: 8 -> 1
    const float b2 = wld(168);
    v2f o2 = (v2f){b2, b2};
#pragma unroll
    for (int i = 0; i < 8; i++) {
        const float wv = wld(144 + i);
        o2 = pkfma((v2f){wv, wv}, h2[i], o2);
    }

    *(v2f*)(logits + (size_t)inst * HW_ + p0) = o2;
}

// K2: aligned_bilinear x2 from fp32 logits. 1 thread = 2x4 output block
// (two adjacent 2x2 quads -> float4 row stores). Pure bandwidth, tiny VGPR.
//   out[2r  ,2c  ] = 0.25*(L[r-1,c-1]+L[r-1,c]+L[r,c-1]+L[r,c])
//   out[2r  ,2c+1] = 0.5 *(L[r-1,c]+L[r,c])
//   out[2r+1,2c  ] = 0.5 *(L[r,c-1]+L[r,c])
//   out[2r+1,2c+1] =       L[r,c]        (r-1, c-1 clamped at 0)
__global__ __launch_bounds__(256) void upsample_kernel(
    const float* __restrict__ logits,  // (128, HW_)
    const void*  __restrict__ soi_v,   // dtype probe
    void*        __restrict__ out_v)   // (128,1,256,384)
{
    const bool f32in = (*(const unsigned int*)soi_v) == 0x42800000u;

    const int inst = blockIdx.y;
    const int t  = blockIdx.x * 256 + threadIdx.x;   // 0..12287
    const int r  = t / 96;
    const int cp = t - r * 96;
    const int c  = 2 * cp;                           // 0..190, even
    const int cm = c ? c - 1 : 0;
    const int rm = r ? r - 1 : 0;

    const float* L  = logits + (size_t)inst * HW_;
    const float* rU = L + rm * W_;
    const float* rD = L + r * W_;

    const float  aL  = rU[cm];
    const float2 a01 = *(const float2*)(rU + c);     // 8B aligned
    const float  dL  = rD[cm];
    const float2 d01 = *(const float2*)(rD + c);

    // quad at col c
    const float v00 = 0.25f * (aL + a01.x + dL + d01.x);
    const float v01 = 0.5f  * (a01.x + d01.x);
    const float v10 = 0.5f  * (dL + d01.x);
    const float v11 = d01.x;
    // quad at col c+1 (left neighbor is col c)
    const float u00 = 0.25f * (a01.x + a01.y + d01.x + d01.y);
    const float u01 = 0.5f  * (a01.y + d01.y);
    const float u10 = 0.5f  * (d01.x + d01.y);
    const float u11 = d01.y;

    const size_t base = ((size_t)inst * OH_ + 2 * r) * (size_t)OW_ + 2 * c;
    if (f32in) {
        float* of = (float*)out_v;
        *(float4*)(of + base)       = make_float4(v00, v01, u00, u01);  // 16B aligned
        *(float4*)(of + base + OW_) = make_float4(v10, v11, u10, u11);
    } else {
        unsigned int* ob = (unsigned int*)out_v;
        const size_t i0 = base >> 1;
        ob[i0]     = f2bf(v00) | (f2bf(v01) << 16);
        ob[i0 + 1] = f2bf(u00) | (f2bf(u01) << 16);
        const size_t i1 = (base + OW_) >> 1;
        ob[i1]     = f2bf(v10) | (f2bf(v11) << 16);
        ob[i1 + 1] = f2bf(u10) | (f2bf(u11) << 16);
    }
}

extern "C" void kernel_launch(void* const* d_in, const int* in_sizes, int n_in,
                              void* d_out, int out_size, void* d_ws, size_t ws_size,
                              hipStream_t stream) {
    (void)in_sizes; (void)n_in; (void)ws_size; (void)out_size;
    float* logits = (float*)d_ws;   // 12.6 MB fp32 scratch

    dim3 g1(HW_ / (256 * 2), NUM_INST);   // (48, 128)
    mlp_kernel<<<g1, 256, 0, stream>>>(d_in[0], d_in[1], d_in[2], d_in[3],
                                       (const int*)d_in[4], (const int*)d_in[5],
                                       logits);

    dim3 g2((H_ * (W_ / 2)) / 256, NUM_INST);  // (48, 128)
    upsample_kernel<<<g2, 256, 0, stream>>>(logits, d_in[3], d_out);
}

// Round 7
// 101.779 us; speedup vs baseline: 8.2296x; 8.2296x over previous
//
#include <hip/hip_runtime.h>

// DynamicMaskHead: N=2, C=8, H=128, W=192, n_inst=128, factor=2. All fp32
// (proven R4: WRITE_SIZE == 48 MiB == fp32 output, test passed).
#define NUM_INST 128
#define H_ 128
#define W_ 192
#define HW_ (H_ * W_)      // 24576
#define OH_ 256
#define OW_ 384
#define NPAR 169           // 80 + 64 + 8 + 8 + 8 + 1

typedef float v2f __attribute__((ext_vector_type(2)));

static __device__ __forceinline__ v2f pkfma(v2f a, v2f b, v2f c) {
    return __builtin_elementwise_fma(a, b, c);   // v_pk_fma_f32
}
static __device__ __forceinline__ v2f pkrelu(v2f a) {
    const v2f z = {0.0f, 0.0f};
    return __builtin_elementwise_max(a, z);
}

// K1: dynamic 3-layer MLP -> fp32 logits. 2 px/thread.
// Weights: pw[k] with wave-uniform base (inst = blockIdx.y) and constant k
// -> compiler scalarizes to s_load / SGPR operands. ZERO LDS, no barrier.
// R6 post-mortem: a runtime-dtype lambda around these loads broke
// scalarization and spilled weight arrays to scratch (683MB fetch, 1.3GB
// write, 765us). Straight-line fp32 code restores the scalar path.
__global__ __launch_bounds__(256) void mlp_kernel(
    const float* __restrict__ mask_feats, // (2,8,128,192)
    const float* __restrict__ params,     // (128,169)
    const float* __restrict__ inst_loc,   // (128,2)
    const float* __restrict__ soi_tab,    // (6,)
    const int*   __restrict__ im_inds,    // (128,)
    const int*   __restrict__ fpn,        // (128,)
    float*       __restrict__ logits)     // (128, HW_) ws
{
    const int inst = blockIdx.y;
    const float* __restrict__ pw = params + (size_t)inst * NPAR;

    const float lx   = inst_loc[inst * 2 + 0];
    const float ly   = inst_loc[inst * 2 + 1];
    const float soi  = soi_tab[fpn[inst]];
    const float invs = 1.0f / soi;
    const float* __restrict__ fb0 = mask_feats + (size_t)im_inds[inst] * 8 * HW_;

    const int p0 = (blockIdx.x * 256 + threadIdx.x) * 2;  // 2 px, same row
    const int r  = p0 / W_;
    const int c0 = p0 - r * W_;

    const float dy  = (ly - (float)(r * 8 + 4)) * invs;
    const float dx0 = (lx - (float)(c0 * 8 + 4)) * invs;

    // inputs: x0 = dx pair, x1..x8 = feature channels (8B-aligned float2)
    const float* fb = fb0 + (r * W_ + c0);
    v2f x0 = (v2f){dx0, dx0 - 8.0f * invs};
    float2 f0 = *(const float2*)(fb + 0 * HW_);
    float2 f1 = *(const float2*)(fb + 1 * HW_);
    float2 f2 = *(const float2*)(fb + 2 * HW_);
    float2 f3 = *(const float2*)(fb + 3 * HW_);
    float2 f4 = *(const float2*)(fb + 4 * HW_);
    float2 f5 = *(const float2*)(fb + 5 * HW_);
    float2 f6 = *(const float2*)(fb + 6 * HW_);
    float2 f7 = *(const float2*)(fb + 7 * HW_);
    v2f x1 = (v2f){f0.x, f0.y}, x2 = (v2f){f1.x, f1.y};
    v2f x3 = (v2f){f2.x, f2.y}, x4 = (v2f){f3.x, f3.y};
    v2f x5 = (v2f){f4.x, f4.y}, x6 = (v2f){f5.x, f5.y};
    v2f x7 = (v2f){f6.x, f6.y}, x8 = (v2f){f7.x, f7.y};

    // layer 0: 10 -> 8, relu. row o: [w_dx, w_dy, w_f0..w_f7]; dy folded
    // into bias (scalar fmaf).
    v2f h1[8];
#pragma unroll
    for (int o = 0; o < 8; o++) {
        const int b = o * 10;
        const float t = fmaf(pw[b + 1], dy, pw[152 + o]);
        v2f a = (v2f){t, t};
        a = pkfma((v2f){pw[b + 0], pw[b + 0]}, x0, a);
        a = pkfma((v2f){pw[b + 2], pw[b + 2]}, x1, a);
        a = pkfma((v2f){pw[b + 3], pw[b + 3]}, x2, a);
        a = pkfma((v2f){pw[b + 4], pw[b + 4]}, x3, a);
        a = pkfma((v2f){pw[b + 5], pw[b + 5]}, x4, a);
        a = pkfma((v2f){pw[b + 6], pw[b + 6]}, x5, a);
        a = pkfma((v2f){pw[b + 7], pw[b + 7]}, x6, a);
        a = pkfma((v2f){pw[b + 8], pw[b + 8]}, x7, a);
        a = pkfma((v2f){pw[b + 9], pw[b + 9]}, x8, a);
        h1[o] = pkrelu(a);
    }

    // layer 1: 8 -> 8, relu
    v2f h2[8];
#pragma unroll
    for (int o = 0; o < 8; o++) {
        const int b = 80 + o * 8;
        const float bb = pw[160 + o];
        v2f a = (v2f){bb, bb};
#pragma unroll
        for (int i = 0; i < 8; i++)
            a = pkfma((v2f){pw[b + i], pw[b + i]}, h1[i], a);
        h2[o] = pkrelu(a);
    }

    // layer 2: 8 -> 1
    v2f o2 = (v2f){pw[168], pw[168]};
#pragma unroll
    for (int i = 0; i < 8; i++)
        o2 = pkfma((v2f){pw[144 + i], pw[144 + i]}, h2[i], o2);

    *(v2f*)(logits + (size_t)inst * HW_ + p0) = o2;
}

// K2: aligned_bilinear x2. 1 thread = 2x4 output block (two adjacent 2x2
// quads -> two float4 row stores). Pure bandwidth, tiny VGPR.
//   out[2r  ,2c  ] = 0.25*(L[r-1,c-1]+L[r-1,c]+L[r,c-1]+L[r,c])
//   out[2r  ,2c+1] = 0.5 *(L[r-1,c]+L[r,c])
//   out[2r+1,2c  ] = 0.5 *(L[r,c-1]+L[r,c])
//   out[2r+1,2c+1] =       L[r,c]        (r-1, c-1 clamped at 0)
__global__ __launch_bounds__(256) void upsample_kernel(
    const float* __restrict__ logits,  // (128, HW_)
    float*       __restrict__ out)     // (128,1,256,384)
{
    const int inst = blockIdx.y;
    const int t  = blockIdx.x * 256 + threadIdx.x;   // 0..12287
    const int r  = t / 96;
    const int cp = t - r * 96;
    const int c  = 2 * cp;                           // 0..190, even
    const int cm = c ? c - 1 : 0;
    const int rm = r ? r - 1 : 0;

    const float* L  = logits + (size_t)inst * HW_;
    const float* rU = L + rm * W_;
    const float* rD = L + r * W_;

    const float  aL  = rU[cm];
    const float2 a01 = *(const float2*)(rU + c);     // 8B aligned
    const float  dL  = rD[cm];
    const float2 d01 = *(const float2*)(rD + c);

    // quad at col c
    const float v00 = 0.25f * (aL + a01.x + dL + d01.x);
    const float v01 = 0.5f  * (a01.x + d01.x);
    const float v10 = 0.5f  * (dL + d01.x);
    const float v11 = d01.x;
    // quad at col c+1 (left neighbor is col c)
    const float u00 = 0.25f * (a01.x + a01.y + d01.x + d01.y);
    const float u01 = 0.5f  * (a01.y + d01.y);
    const float u10 = 0.5f  * (d01.x + d01.y);
    const float u11 = d01.y;

    const size_t base = ((size_t)inst * OH_ + 2 * r) * (size_t)OW_ + 2 * c;
    *(float4*)(out + base)       = make_float4(v00, v01, u00, u01);  // 16B aligned
    *(float4*)(out + base + OW_) = make_float4(v10, v11, u10, u11);
}

extern "C" void kernel_launch(void* const* d_in, const int* in_sizes, int n_in,
                              void* d_out, int out_size, void* d_ws, size_t ws_size,
                              hipStream_t stream) {
    (void)in_sizes; (void)n_in; (void)ws_size; (void)out_size;
    const float* mask_feats = (const float*)d_in[0];
    const float* params     = (const float*)d_in[1];
    const float* inst_loc   = (const float*)d_in[2];
    const float* soi_tab    = (const float*)d_in[3];
    const int*   im_inds    = (const int*)d_in[4];
    const int*   fpn_levels = (const int*)d_in[5];
    float* logits = (float*)d_ws;   // 12.6 MB fp32 scratch

    dim3 g1(HW_ / (256 * 2), NUM_INST);   // (48, 128)
    mlp_kernel<<<g1, 256, 0, stream>>>(mask_feats, params, inst_loc, soi_tab,
                                       im_inds, fpn_levels, logits);

    dim3 g2((H_ * (W_ / 2)) / 256, NUM_INST);  // (48, 128)
    upsample_kernel<<<g2, 256, 0, stream>>>(logits, (float*)d_out);
}